// Round 8
// baseline (243.763 us; speedup 1.0000x reference)
//
#include <hip/hip_runtime.h>
#include <hip/hip_bf16.h>

// Causal flash attention fwd. B=2,H=16,S=2048,D=128, fp32 io, bf16 MFMA.
// R10: split-K load balance. R7/R8/R9 all ~93us with identical counters:
// Occupancy 13% = avg(nkt)/max(nkt) = 17/32 -> half the machine idles while
// qt=15 CUs grind a 32-round sequential chain (grid=512=2/CU, no queue;
// round-robin puts same-qt blocks on one CU). Fix: online softmax is
// mergeable -> cut the 272 (qt,kt) units/head into 16 chunks of exactly 17
// units. Every block now does 17 rounds -> duty ~100%, makespan ~halved.
// Boundary-crossing q-tiles write fp32 partials (O unnorm + m,l) to ws;
// a second kernel merges (<=3 segments/qtile). ws_size runtime-checked;
// fallback = whole-tile path (R7 schedule, known-pass). Inner round
// unchanged from R7/R9 (32x32x16, swizzles, permlane P, defer-max).
constexpr int Bb = 2, Hh = 16, Ss = 2048, Dd = 128;
constexpr int BM = 128, BN = 64;
constexpr int NQT = Ss / BM;                       // 16
constexpr float SCALE = 0.088388347648318447f * 1.4426950408889634f; // 1/sqrt(128)*log2e

typedef __attribute__((ext_vector_type(8))) short bf16x8;
typedef __attribute__((ext_vector_type(16))) float f32x16;
typedef __attribute__((ext_vector_type(4))) int int4v;

// Segment tables: chunk c covers units [17c,17c+17) of the per-head list
// (units = (qt,kt), qt-major; qt starts at qt*(qt+1), length 2qt+2).
// Each chunk sums to exactly 17 k-tile rounds. Max 3 segments per qt.
__device__ const int SEG_OFF[17] = {0,4,7,9,11,13,15,17,19,20,22,24,25,27,28,30,31};
__device__ const int SEG_QT[31]  = {0,1,2,3, 3,4,5, 5,6, 6,7, 7,8, 8,9, 9,10, 10,11, 11, 11,12, 12,13, 13, 13,14, 14, 14,15, 15};
__device__ const int SEG_K0[31]  = {0,0,0,0, 5,0,0, 4,0, 9,0, 12,0, 13,0, 12,0, 9,0, 4, 21,0, 14,0, 5, 22,0, 11, 28,0, 15};
__device__ const int SEG_K1[31]  = {2,4,6,5, 8,10,4, 12,9, 14,12, 16,13, 18,12, 20,9, 22,4, 21, 24,14, 26,5, 22, 28,11, 28, 30,15, 32};
__device__ const int SEG_LOC[31] = {0,0,0,0, 1,0,0, 1,0, 1,0, 1,0, 1,0, 1,0, 1,0, 1, 2,0, 1,0, 1, 2,0, 1, 2,0, 1};
__device__ const int QT_NSEG[16] = {1,1,1,2,1,2,2,2,2,2,2,3,2,3,3,2};

__device__ __forceinline__ unsigned cvtpk(float lo, float hi) {
  unsigned r;
  asm("v_cvt_pk_bf16_f32 %0, %1, %2" : "=v"(r) : "v"(lo), "v"(hi));
  return r;                                    // RNE packed bf16 pair
}
__device__ __forceinline__ float exp2hw(float x) {
  float r;
  asm("v_exp_f32 %0, %1" : "=v"(r) : "v"(x));  // hardware exp2
  return r;
}
// exchange x.lanes[32:63] <-> y.lanes[0:31]
__device__ __forceinline__ void permswap(unsigned &x, unsigned &y) {
  asm("v_permlane32_swap_b32 %0, %1" : "+v"(x), "+v"(y));
}
__device__ __forceinline__ float fcomp(float4 f, int j) {   // j is unroll-constant
  return j == 0 ? f.x : (j == 1 ? f.y : (j == 2 ? f.z : f.w));
}
// Barrier without vmcnt drain (LDS visibility only).
__device__ __forceinline__ void block_sync_lds() {
  __builtin_amdgcn_sched_barrier(0);
  asm volatile("s_waitcnt lgkmcnt(0)" ::: "memory");
  __builtin_amdgcn_s_barrier();
  __builtin_amdgcn_sched_barrier(0);
}

__global__ __launch_bounds__(256, 2)
void fa_seg_kernel(const float* __restrict__ q, const float* __restrict__ k,
                   const float* __restrict__ v, float* __restrict__ out,
                   float* __restrict__ wsO, float* __restrict__ wsML) {
  __shared__ __align__(16) char Klds[2][BN * 256];    // 2 x 16 KB, swizzled
  __shared__ __align__(16) char Vlds[2][Dd * 128];    // 2 x 16 KB, swizzled

  const int tid = threadIdx.x;
  const int wave = tid >> 6, lane = tid & 63;
  const int l31 = lane & 31, hi = lane >> 5, hi4 = hi * 4;
  const int bid = blockIdx.x;
  const bool wsmode = (wsO != nullptr);

  int bh, si0, si1, qt_fb = 0;
  if (wsmode) {                       // balanced chunk mode
    bh = bid >> 4;
    const int chunk = bid & 15;
    si0 = SEG_OFF[chunk]; si1 = SEG_OFF[chunk + 1];
  } else {                            // fallback: one full q-tile per block
    bh = bid & 31;
    const int r2 = bid >> 5;
    qt_fb = (r2 < 8) ? (15 - r2) : (r2 - 8);
    si0 = 0; si1 = 1;
  }

  const float* qb = q + (size_t)bh * Ss * Dd;
  const float* kb = k + (size_t)bh * Ss * Dd;
  const float* vb = v + (size_t)bh * Ss * Dd;
  const int qloc = wave * 32 + l31;       // q-row within tile this lane owns

  // staging geometry (constant per thread)
  const int krow0 = tid >> 4, kblk = tid & 15, kswz = kblk ^ krow0;
  const int vkg = tid >> 5, vdq = tid & 31;

  float4 ka[4], kc[4];                    // K prefetch regs
  float4 vr[8];                           // V prefetch regs

  auto load_k = [&](int kt) {
    const float* Kg = kb + (size_t)(kt * BN) * Dd + kblk * 8;
    #pragma unroll
    for (int i = 0; i < 4; ++i) {
      ka[i] = *(const float4*)(Kg + (size_t)(krow0 + 16 * i) * Dd);
      kc[i] = *(const float4*)(Kg + (size_t)(krow0 + 16 * i) * Dd + 4);
    }
  };
  auto load_v = [&](int kt) {
    const float* Vg = vb + (size_t)(kt * BN + vkg * 8) * Dd + vdq * 4;
    #pragma unroll
    for (int r = 0; r < 8; ++r)
      vr[r] = *(const float4*)(Vg + (size_t)r * Dd);
  };
  auto stage_k = [&](char* Kb) {
    #pragma unroll
    for (int i = 0; i < 4; ++i) {
      int4v t;
      t[0] = (int)cvtpk(ka[i].x, ka[i].y);
      t[1] = (int)cvtpk(ka[i].z, ka[i].w);
      t[2] = (int)cvtpk(kc[i].x, kc[i].y);
      t[3] = (int)cvtpk(kc[i].z, kc[i].w);
      *(int4v*)(Kb + (krow0 + 16 * i) * 256 + kswz * 16) = t;
    }
  };
  auto stage_v = [&](char* Vb) {
    #pragma unroll
    for (int j = 0; j < 4; ++j) {
      int d = vdq * 4 + j;
      int f7 = (d ^ (d >> 3)) & 7;
      int4v t;
      t[0] = (int)cvtpk(fcomp(vr[0], j), fcomp(vr[1], j));
      t[1] = (int)cvtpk(fcomp(vr[2], j), fcomp(vr[3], j));
      t[2] = (int)cvtpk(fcomp(vr[4], j), fcomp(vr[5], j));
      t[3] = (int)cvtpk(fcomp(vr[6], j), fcomp(vr[7], j));
      *(int4v*)(Vb + d * 128 + (vkg ^ f7) * 16) = t;
    }
  };

  for (int si = si0; si < si1; ++si) {
    const int qt  = wsmode ? SEG_QT[si] : qt_fb;
    const int kt0 = wsmode ? SEG_K0[si] : 0;
    const int nkt = 2 * qt + 2;
    const int kte = wsmode ? SEG_K1[si] : nkt;
    const int loc = wsmode ? SEG_LOC[si] : 0;
    const bool isfull = (kt0 == 0) && (kte == nkt);
    const int nloc = kte - kt0;

    // ---- Q fragments for this q-tile (scale*log2e folded).
    bf16x8 qf[8];
    {
      const float* qr = qb + (size_t)(qt * BM + qloc) * Dd + hi * 8;
      #pragma unroll
      for (int ks = 0; ks < 8; ++ks) {
        float4 a = *(const float4*)(qr + ks * 16);
        float4 b = *(const float4*)(qr + ks * 16 + 4);
        int4v t;
        t[0] = (int)cvtpk(a.x * SCALE, a.y * SCALE);
        t[1] = (int)cvtpk(a.z * SCALE, a.w * SCALE);
        t[2] = (int)cvtpk(b.x * SCALE, b.y * SCALE);
        t[3] = (int)cvtpk(b.z * SCALE, b.w * SCALE);
        qf[ks] = __builtin_bit_cast(bf16x8, t);
      }
    }

    f32x16 o[4];
    #pragma unroll
    for (int i = 0; i < 4; ++i) o[i] = (f32x16)(0.0f);
    float mrow = -3.0e38f, lrow = 0.0f;

    // segment prologue: protect LDS from previous segment's readers, stage tile kt0
    load_k(kt0); load_v(kt0);
    block_sync_lds();
    stage_k(&Klds[0][0]); stage_v(&Vlds[0][0]);

    for (int i = 0; i < nloc; ++i) {
      block_sync_lds();                  // buf[cur] staged & visible
      const int kt = kt0 + i;
      const int cur = i & 1;
      const char* Kc = &Klds[cur][0];
      const char* Vc = &Vlds[cur][0];
      const bool more = i + 1 < nloc;
      if (more) load_k(kt + 1);

      const int thr = qt * 128 + qloc - kt * 64;
      const bool live = (qt * 128 + wave * 32 + 31 - kt * 64) >= 0;  // wave-uniform

      bf16x8 pf[4];
      if (live) {
        // S^T = K Q^T. D col=q=l31, row(key)=t*32+(reg&3)+8*(reg>>2)+4*hi.
        f32x16 acc[2];
        acc[0] = (f32x16)(0.0f); acc[1] = (f32x16)(0.0f);
        __builtin_amdgcn_s_setprio(1);
        #pragma unroll
        for (int ks = 0; ks < 8; ++ks) {
          #pragma unroll
          for (int t = 0; t < 2; ++t) {
            int row = t * 32 + l31;
            int bswz = (2 * ks + hi) ^ (row & 15);
            bf16x8 kf = *(const bf16x8*)(Kc + row * 256 + bswz * 16);
            acc[t] = __builtin_amdgcn_mfma_f32_32x32x16_bf16(kf, qf[ks], acc[t], 0, 0, 0);
          }
        }
        __builtin_amdgcn_s_setprio(0);

        if (kt + 2 >= nkt) {             // diagonal tiles: causal mask
          #pragma unroll
          for (int t = 0; t < 2; ++t)
            #pragma unroll
            for (int r = 0; r < 16; ++r) {
              int key = t * 32 + (r & 3) + 8 * (r >> 2) + hi4;
              if (key > thr) acc[t][r] = -1.0e30f;
            }
        }

        // online softmax (log2 domain), 4-way tree partials
        float mp0 = acc[0][0], mp1 = acc[0][1], mp2 = acc[0][2], mp3 = acc[0][3];
        #pragma unroll
        for (int t = 0; t < 2; ++t)
          #pragma unroll
          for (int r = (t == 0 ? 4 : 0); r < 16; r += 4) {
            mp0 = fmaxf(mp0, acc[t][r + 0]);
            mp1 = fmaxf(mp1, acc[t][r + 1]);
            mp2 = fmaxf(mp2, acc[t][r + 2]);
            mp3 = fmaxf(mp3, acc[t][r + 3]);
          }
        float mx = fmaxf(fmaxf(mp0, mp1), fmaxf(mp2, mp3));
        mx = fmaxf(mx, __shfl_xor(mx, 32, 64));

        if (!__all(mx - mrow <= 8.0f)) { // defer-max THR=8
          float mn = fmaxf(mrow, mx);
          float al = exp2hw(mrow - mn);
          mrow = mn;
          lrow *= al;
          #pragma unroll
          for (int dt = 0; dt < 4; ++dt)
            #pragma unroll
            for (int r = 0; r < 16; ++r) o[dt][r] *= al;
        }

        float rp0 = 0.f, rp1 = 0.f, rp2 = 0.f, rp3 = 0.f;
        #pragma unroll
        for (int t = 0; t < 2; ++t)
          #pragma unroll
          for (int r = 0; r < 16; r += 4) {
            float p0 = exp2hw(acc[t][r + 0] - mrow);
            float p1 = exp2hw(acc[t][r + 1] - mrow);
            float p2 = exp2hw(acc[t][r + 2] - mrow);
            float p3 = exp2hw(acc[t][r + 3] - mrow);
            acc[t][r + 0] = p0; acc[t][r + 1] = p1;
            acc[t][r + 2] = p2; acc[t][r + 3] = p3;
            rp0 += p0; rp1 += p1; rp2 += p2; rp3 += p3;
          }
        lrow += (rp0 + rp1) + (rp2 + rp3);

        // P^T B-frags via cvt_pk + permlane32_swap
        #pragma unroll
        for (int ks2 = 0; ks2 < 4; ++ks2) {
          int t = ks2 >> 1, s8 = (ks2 & 1) * 8;
          unsigned A0 = cvtpk(acc[t][s8 + 0], acc[t][s8 + 1]);
          unsigned A1 = cvtpk(acc[t][s8 + 2], acc[t][s8 + 3]);
          unsigned B0 = cvtpk(acc[t][s8 + 4], acc[t][s8 + 5]);
          unsigned B1 = cvtpk(acc[t][s8 + 6], acc[t][s8 + 7]);
          permswap(A0, B0);
          permswap(A1, B1);
          int4v pw; pw[0] = (int)A0; pw[1] = (int)A1; pw[2] = (int)B0; pw[3] = (int)B1;
          pf[ks2] = __builtin_bit_cast(bf16x8, pw);
        }
      }

      if (more) stage_k(&Klds[cur ^ 1][0]);
      __builtin_amdgcn_sched_barrier(0);
      if (more) load_v(kt + 1);

      if (live) {
        __builtin_amdgcn_s_setprio(1);
        #pragma unroll
        for (int dt = 0; dt < 4; ++dt) {
          int row = dt * 32 + l31;
          int f7 = (row ^ (row >> 3)) & 7;
          #pragma unroll
          for (int ks2 = 0; ks2 < 4; ++ks2) {
            int bswz = (2 * ks2 + hi) ^ f7;
            bf16x8 vf = *(const bf16x8*)(Vc + row * 128 + bswz * 16);
            o[dt] = __builtin_amdgcn_mfma_f32_32x32x16_bf16(vf, pf[ks2], o[dt], 0, 0, 0);
          }
        }
        __builtin_amdgcn_s_setprio(0);
      }

      if (more) stage_v(&Vlds[cur ^ 1][0]);
    }

    // ---- segment epilogue
    float lsum = lrow + __shfl_xor(lrow, 32, 64);
    if (isfull) {
      const float linv = 1.0f / lsum;
      float* ob = out + ((size_t)bh * Ss + qt * BM + qloc) * Dd;
      #pragma unroll
      for (int dt = 0; dt < 4; ++dt)
        #pragma unroll
        for (int g = 0; g < 4; ++g) {
          float4 w;
          w.x = o[dt][g * 4 + 0] * linv;
          w.y = o[dt][g * 4 + 1] * linv;
          w.z = o[dt][g * 4 + 2] * linv;
          w.w = o[dt][g * 4 + 3] * linv;
          *(float4*)(ob + dt * 32 + g * 8 + hi4) = w;
        }
    } else {
      // partial: O unnormalized (ref max = mrow) + m,l per row
      const int slot = (bh * 16 + qt) * 3 + loc;
      float* po = wsO + (size_t)slot * 16384 + (size_t)qloc * 128;
      #pragma unroll
      for (int dt = 0; dt < 4; ++dt)
        #pragma unroll
        for (int g = 0; g < 4; ++g) {
          float4 w;
          w.x = o[dt][g * 4 + 0]; w.y = o[dt][g * 4 + 1];
          w.z = o[dt][g * 4 + 2]; w.w = o[dt][g * 4 + 3];
          *(float4*)(po + dt * 32 + g * 8 + hi4) = w;
        }
      if (hi == 0) {
        wsML[(size_t)slot * 256 + qloc]       = mrow;
        wsML[(size_t)slot * 256 + 128 + qloc] = lsum;
      }
    }
  }
}

__global__ __launch_bounds__(256)
void fa_merge_kernel(const float* __restrict__ wsO, const float* __restrict__ wsML,
                     float* __restrict__ out) {
  const int bid = blockIdx.x;          // bh*16 + qt
  const int qt = bid & 15, bh = bid >> 4;
  const int ns = QT_NSEG[qt];
  if (ns < 2) return;                  // full tiles already written by main
  const int t = threadIdx.x;
  const size_t s0 = (size_t)bid * 3;
  const float* O0 = wsO + (s0 + 0) * 16384;
  const float* O1 = wsO + (s0 + 1) * 16384;
  const float* O2 = wsO + (s0 + 2) * 16384;
  const float* M0 = wsML + (s0 + 0) * 256;
  const float* M1 = wsML + (s0 + 1) * 256;
  const float* M2 = wsML + (s0 + 2) * 256;
  float* ob = out + ((size_t)bh * Ss + qt * 128) * Dd;
  #pragma unroll
  for (int i = 0; i < 16; ++i) {
    int e4 = t + 256 * i;              // float4 index in 128x128 tile
    int row = e4 >> 5, dof = (e4 & 31) * 4;
    float m0 = M0[row], l0 = M0[128 + row];
    float m1 = M1[row], l1 = M1[128 + row];
    float m2 = -3.0e38f, l2 = 0.0f;
    if (ns == 3) { m2 = M2[row]; l2 = M2[128 + row]; }
    float M = fmaxf(fmaxf(m0, m1), m2);
    float w0 = exp2hw(m0 - M), w1 = exp2hw(m1 - M);
    float w2 = (ns == 3) ? exp2hw(m2 - M) : 0.0f;
    float Li = 1.0f / (l0 * w0 + l1 * w1 + l2 * w2);
    float4 a = *(const float4*)(O0 + (size_t)row * 128 + dof);
    float4 b = *(const float4*)(O1 + (size_t)row * 128 + dof);
    float4 r;
    r.x = a.x * w0 + b.x * w1; r.y = a.y * w0 + b.y * w1;
    r.z = a.z * w0 + b.z * w1; r.w = a.w * w0 + b.w * w1;
    if (ns == 3) {
      float4 c = *(const float4*)(O2 + (size_t)row * 128 + dof);
      r.x += c.x * w2; r.y += c.y * w2; r.z += c.z * w2; r.w += c.w * w2;
    }
    r.x *= Li; r.y *= Li; r.z *= Li; r.w *= Li;
    *(float4*)(ob + (size_t)row * Dd + dof) = r;
  }
}

extern "C" void kernel_launch(void* const* d_in, const int* in_sizes, int n_in,
                              void* d_out, int out_size, void* d_ws, size_t ws_size,
                              hipStream_t stream) {
  const float* q = (const float*)d_in[0];
  const float* k = (const float*)d_in[1];
  const float* v = (const float*)d_in[2];
  float* out = (float*)d_out;
  constexpr size_t SLOTS = 32 * 16 * 3;                    // 1536
  constexpr size_t NEED_O  = SLOTS * 16384 * sizeof(float); // ~100.7 MB
  constexpr size_t NEED_ML = SLOTS * 256 * sizeof(float);   // ~1.6 MB
  const bool split = (d_ws != nullptr) && (ws_size >= NEED_O + NEED_ML);
  float* wsO  = split ? (float*)d_ws : nullptr;
  float* wsML = split ? ((float*)d_ws + SLOTS * 16384) : nullptr;
  dim3 block(256);
  hipLaunchKernelGGL(fa_seg_kernel, dim3(512), block, 0, stream, q, k, v, out, wsO, wsML);
  if (split)
    hipLaunchKernelGGL(fa_merge_kernel, dim3(512), block, 0, stream, wsO, wsML, out);
}

// Round 11
// 208.180 us; speedup vs baseline: 1.1709x; 1.1709x over previous
//
#include <hip/hip_runtime.h>
#include <hip/hip_bf16.h>

// Causal flash attention fwd. B=2,H=16,S=2048,D=128, fp32 io, bf16 MFMA.
// R11b (resubmit; last round was a container-acquisition failure, no data).
// R10 proved balance (occ 13->18) but its ~100MB ws stream pushed the
// working set past the 256MB L3 -> warm K/V evicted, FETCH 49->308MB.
// R11: pair q-tiles (c,15-c)=34 rounds, split at 17 -> 16 equal chunks/bh
// (pure arithmetic); only the 8 heavy tiles/bh write partials (ws=32.5MB);
// partials use NONTEMPORAL stores/loads (f32x4v ext-vector for the builtin)
// so the stream doesn't evict warm inputs. Inner round identical to R9
// (32x32x16, swizzles, permlane P, defer-max, lgkmcnt-only barrier).
// Fallback whole-tile path if ws too small.
constexpr int Bb = 2, Hh = 16, Ss = 2048, Dd = 128;
constexpr int BM = 128, BN = 64;
constexpr int NQT = Ss / BM;                       // 16
constexpr float SCALE = 0.088388347648318447f * 1.4426950408889634f; // 1/sqrt(128)*log2e

typedef __attribute__((ext_vector_type(8))) short bf16x8;
typedef __attribute__((ext_vector_type(16))) float f32x16;
typedef __attribute__((ext_vector_type(4))) float f32x4v;
typedef __attribute__((ext_vector_type(4))) int int4v;

__device__ __forceinline__ unsigned cvtpk(float lo, float hi) {
  unsigned r;
  asm("v_cvt_pk_bf16_f32 %0, %1, %2" : "=v"(r) : "v"(lo), "v"(hi));
  return r;                                    // RNE packed bf16 pair
}
__device__ __forceinline__ float exp2hw(float x) {
  float r;
  asm("v_exp_f32 %0, %1" : "=v"(r) : "v"(x));  // hardware exp2
  return r;
}
__device__ __forceinline__ void permswap(unsigned &x, unsigned &y) {
  asm("v_permlane32_swap_b32 %0, %1" : "+v"(x), "+v"(y));
}
__device__ __forceinline__ float fcomp(float4 f, int j) {
  return j == 0 ? f.x : (j == 1 ? f.y : (j == 2 ? f.z : f.w));
}
// Barrier without vmcnt drain (LDS visibility only).
__device__ __forceinline__ void block_sync_lds() {
  __builtin_amdgcn_sched_barrier(0);
  asm volatile("s_waitcnt lgkmcnt(0)" ::: "memory");
  __builtin_amdgcn_s_barrier();
  __builtin_amdgcn_sched_barrier(0);
}

__global__ __launch_bounds__(256, 2)
void fa_seg_kernel(const float* __restrict__ q, const float* __restrict__ k,
                   const float* __restrict__ v, float* __restrict__ out,
                   float* __restrict__ wsO, float* __restrict__ wsML) {
  __shared__ __align__(16) char Klds[2][BN * 256];    // 2 x 16 KB, swizzled
  __shared__ __align__(16) char Vlds[2][Dd * 128];    // 2 x 16 KB, swizzled

  const int tid = threadIdx.x;
  const int wave = tid >> 6, lane = tid & 63;
  const int l31 = lane & 31, hi = lane >> 5, hi4 = hi * 4;
  const int bid = blockIdx.x;
  const bool wsmode = (wsO != nullptr);

  // Segment schedule (all arithmetic). wsmode: chunk = bid>>5, c = chunk>>1.
  //  h=0: seg0 = light tile qt=c, kt [0, 2c+2)   -> full, writes out
  //       seg1 = heavy tile qt=15-c, kt [0,15-2c) -> partial loc 0
  //  h=1: seg0 = heavy tile qt=15-c, kt [15-2c, 32-2c) -> partial loc 1
  // Every chunk = exactly 17 rounds.
  int bh, nseg, sqt[2], sk0[2], sk1[2], sloc[2];
  if (wsmode) {
    bh = bid & 31;
    const int chunk = bid >> 5;
    const int c = chunk >> 1;
    if ((chunk & 1) == 0) {
      nseg = 2;
      sqt[0] = c;      sk0[0] = 0;         sk1[0] = 2 * c + 2;  sloc[0] = 0;
      sqt[1] = 15 - c; sk0[1] = 0;         sk1[1] = 15 - 2 * c; sloc[1] = 0;
    } else {
      nseg = 1;
      sqt[0] = 15 - c; sk0[0] = 15 - 2 * c; sk1[0] = 32 - 2 * c; sloc[0] = 1;
      sqt[1] = 0; sk0[1] = 0; sk1[1] = 0; sloc[1] = 0;
    }
  } else {                                // fallback: one full q-tile per block
    bh = bid & 31;
    const int r2 = bid >> 5;
    const int qf_ = (r2 < 8) ? (15 - r2) : (r2 - 8);
    nseg = 1;
    sqt[0] = qf_; sk0[0] = 0; sk1[0] = 2 * qf_ + 2; sloc[0] = 0;
    sqt[1] = 0; sk0[1] = 0; sk1[1] = 0; sloc[1] = 0;
  }

  const float* qb = q + (size_t)bh * Ss * Dd;
  const float* kb = k + (size_t)bh * Ss * Dd;
  const float* vb = v + (size_t)bh * Ss * Dd;
  const int qloc = wave * 32 + l31;       // q-row within tile this lane owns

  const int krow0 = tid >> 4, kblk = tid & 15, kswz = kblk ^ krow0;
  const int vkg = tid >> 5, vdq = tid & 31;

  float4 ka[4], kc[4];
  float4 vr[8];

  auto load_k = [&](int kt) {
    const float* Kg = kb + (size_t)(kt * BN) * Dd + kblk * 8;
    #pragma unroll
    for (int i = 0; i < 4; ++i) {
      ka[i] = *(const float4*)(Kg + (size_t)(krow0 + 16 * i) * Dd);
      kc[i] = *(const float4*)(Kg + (size_t)(krow0 + 16 * i) * Dd + 4);
    }
  };
  auto load_v = [&](int kt) {
    const float* Vg = vb + (size_t)(kt * BN + vkg * 8) * Dd + vdq * 4;
    #pragma unroll
    for (int r = 0; r < 8; ++r)
      vr[r] = *(const float4*)(Vg + (size_t)r * Dd);
  };
  auto stage_k = [&](char* Kb) {
    #pragma unroll
    for (int i = 0; i < 4; ++i) {
      int4v t;
      t[0] = (int)cvtpk(ka[i].x, ka[i].y);
      t[1] = (int)cvtpk(ka[i].z, ka[i].w);
      t[2] = (int)cvtpk(kc[i].x, kc[i].y);
      t[3] = (int)cvtpk(kc[i].z, kc[i].w);
      *(int4v*)(Kb + (krow0 + 16 * i) * 256 + kswz * 16) = t;
    }
  };
  auto stage_v = [&](char* Vb) {
    #pragma unroll
    for (int j = 0; j < 4; ++j) {
      int d = vdq * 4 + j;
      int f7 = (d ^ (d >> 3)) & 7;
      int4v t;
      t[0] = (int)cvtpk(fcomp(vr[0], j), fcomp(vr[1], j));
      t[1] = (int)cvtpk(fcomp(vr[2], j), fcomp(vr[3], j));
      t[2] = (int)cvtpk(fcomp(vr[4], j), fcomp(vr[5], j));
      t[3] = (int)cvtpk(fcomp(vr[6], j), fcomp(vr[7], j));
      *(int4v*)(Vb + d * 128 + (vkg ^ f7) * 16) = t;
    }
  };

  for (int si = 0; si < nseg; ++si) {
    const int qt  = sqt[si];
    const int kt0 = sk0[si];
    const int kte = sk1[si];
    const int loc = sloc[si];
    const int nkt = 2 * qt + 2;
    const bool isfull = (kt0 == 0) && (kte == nkt);
    const int nloc = kte - kt0;

    bf16x8 qf[8];
    {
      const float* qr = qb + (size_t)(qt * BM + qloc) * Dd + hi * 8;
      #pragma unroll
      for (int ks = 0; ks < 8; ++ks) {
        float4 a = *(const float4*)(qr + ks * 16);
        float4 b = *(const float4*)(qr + ks * 16 + 4);
        int4v t;
        t[0] = (int)cvtpk(a.x * SCALE, a.y * SCALE);
        t[1] = (int)cvtpk(a.z * SCALE, a.w * SCALE);
        t[2] = (int)cvtpk(b.x * SCALE, b.y * SCALE);
        t[3] = (int)cvtpk(b.z * SCALE, b.w * SCALE);
        qf[ks] = __builtin_bit_cast(bf16x8, t);
      }
    }

    f32x16 o[4];
    #pragma unroll
    for (int i = 0; i < 4; ++i) o[i] = (f32x16)(0.0f);
    float mrow = -3.0e38f, lrow = 0.0f;

    // segment prologue: protect LDS from previous segment's readers
    load_k(kt0); load_v(kt0);
    block_sync_lds();
    stage_k(&Klds[0][0]); stage_v(&Vlds[0][0]);

    for (int i = 0; i < nloc; ++i) {
      block_sync_lds();                  // buf[cur] staged & visible
      const int kt = kt0 + i;
      const int cur = i & 1;
      const char* Kc = &Klds[cur][0];
      const char* Vc = &Vlds[cur][0];
      const bool more = i + 1 < nloc;
      if (more) load_k(kt + 1);

      const int thr = qt * 128 + qloc - kt * 64;
      // All rounds in every segment are live (by construction of the split).

      bf16x8 pf[4];
      {
        f32x16 acc[2];
        acc[0] = (f32x16)(0.0f); acc[1] = (f32x16)(0.0f);
        __builtin_amdgcn_s_setprio(1);
        #pragma unroll
        for (int ks = 0; ks < 8; ++ks) {
          #pragma unroll
          for (int t = 0; t < 2; ++t) {
            int row = t * 32 + l31;
            int bswz = (2 * ks + hi) ^ (row & 15);
            bf16x8 kf = *(const bf16x8*)(Kc + row * 256 + bswz * 16);
            acc[t] = __builtin_amdgcn_mfma_f32_32x32x16_bf16(kf, qf[ks], acc[t], 0, 0, 0);
          }
        }
        __builtin_amdgcn_s_setprio(0);

        if (kt + 2 >= nkt) {             // diagonal tiles: causal mask
          #pragma unroll
          for (int t = 0; t < 2; ++t)
            #pragma unroll
            for (int r = 0; r < 16; ++r) {
              int key = t * 32 + (r & 3) + 8 * (r >> 2) + hi4;
              if (key > thr) acc[t][r] = -1.0e30f;
            }
        }

        // online softmax (log2 domain), 4-way tree partials
        float mp0 = acc[0][0], mp1 = acc[0][1], mp2 = acc[0][2], mp3 = acc[0][3];
        #pragma unroll
        for (int t = 0; t < 2; ++t)
          #pragma unroll
          for (int r = (t == 0 ? 4 : 0); r < 16; r += 4) {
            mp0 = fmaxf(mp0, acc[t][r + 0]);
            mp1 = fmaxf(mp1, acc[t][r + 1]);
            mp2 = fmaxf(mp2, acc[t][r + 2]);
            mp3 = fmaxf(mp3, acc[t][r + 3]);
          }
        float mx = fmaxf(fmaxf(mp0, mp1), fmaxf(mp2, mp3));
        mx = fmaxf(mx, __shfl_xor(mx, 32, 64));

        if (!__all(mx - mrow <= 8.0f)) { // defer-max THR=8
          float mn = fmaxf(mrow, mx);
          float al = exp2hw(mrow - mn);
          mrow = mn;
          lrow *= al;
          #pragma unroll
          for (int dt = 0; dt < 4; ++dt)
            #pragma unroll
            for (int r = 0; r < 16; ++r) o[dt][r] *= al;
        }

        float rp0 = 0.f, rp1 = 0.f, rp2 = 0.f, rp3 = 0.f;
        #pragma unroll
        for (int t = 0; t < 2; ++t)
          #pragma unroll
          for (int r = 0; r < 16; r += 4) {
            float p0 = exp2hw(acc[t][r + 0] - mrow);
            float p1 = exp2hw(acc[t][r + 1] - mrow);
            float p2 = exp2hw(acc[t][r + 2] - mrow);
            float p3 = exp2hw(acc[t][r + 3] - mrow);
            acc[t][r + 0] = p0; acc[t][r + 1] = p1;
            acc[t][r + 2] = p2; acc[t][r + 3] = p3;
            rp0 += p0; rp1 += p1; rp2 += p2; rp3 += p3;
          }
        lrow += (rp0 + rp1) + (rp2 + rp3);

        // P^T B-frags via cvt_pk + permlane32_swap
        #pragma unroll
        for (int ks2 = 0; ks2 < 4; ++ks2) {
          int t = ks2 >> 1, s8 = (ks2 & 1) * 8;
          unsigned A0 = cvtpk(acc[t][s8 + 0], acc[t][s8 + 1]);
          unsigned A1 = cvtpk(acc[t][s8 + 2], acc[t][s8 + 3]);
          unsigned B0 = cvtpk(acc[t][s8 + 4], acc[t][s8 + 5]);
          unsigned B1 = cvtpk(acc[t][s8 + 6], acc[t][s8 + 7]);
          permswap(A0, B0);
          permswap(A1, B1);
          int4v pw; pw[0] = (int)A0; pw[1] = (int)A1; pw[2] = (int)B0; pw[3] = (int)B1;
          pf[ks2] = __builtin_bit_cast(bf16x8, pw);
        }
      }

      if (more) stage_k(&Klds[cur ^ 1][0]);
      __builtin_amdgcn_sched_barrier(0);
      if (more) load_v(kt + 1);

      {
        __builtin_amdgcn_s_setprio(1);
        #pragma unroll
        for (int dt = 0; dt < 4; ++dt) {
          int row = dt * 32 + l31;
          int f7 = (row ^ (row >> 3)) & 7;
          #pragma unroll
          for (int ks2 = 0; ks2 < 4; ++ks2) {
            int bswz = (2 * ks2 + hi) ^ f7;
            bf16x8 vf = *(const bf16x8*)(Vc + row * 128 + bswz * 16);
            o[dt] = __builtin_amdgcn_mfma_f32_32x32x16_bf16(vf, pf[ks2], o[dt], 0, 0, 0);
          }
        }
        __builtin_amdgcn_s_setprio(0);
      }

      if (more) stage_v(&Vlds[cur ^ 1][0]);
    }

    // ---- segment epilogue
    float lsum = lrow + __shfl_xor(lrow, 32, 64);
    if (isfull) {
      const float linv = 1.0f / lsum;
      float* ob = out + ((size_t)bh * Ss + qt * BM + qloc) * Dd;
      #pragma unroll
      for (int dt = 0; dt < 4; ++dt)
        #pragma unroll
        for (int g = 0; g < 4; ++g) {
          float4 w;
          w.x = o[dt][g * 4 + 0] * linv;
          w.y = o[dt][g * 4 + 1] * linv;
          w.z = o[dt][g * 4 + 2] * linv;
          w.w = o[dt][g * 4 + 3] * linv;
          *(float4*)(ob + dt * 32 + g * 8 + hi4) = w;
        }
    } else {
      // partial (heavy tiles only): slot = ((bh*8 + c)*2 + loc), c = 15-qt.
      const int slot = ((bh * 8 + (15 - qt)) * 2 + loc);
      float* po = wsO + (size_t)slot * 16384 + (size_t)qloc * 128;
      #pragma unroll
      for (int dt = 0; dt < 4; ++dt)
        #pragma unroll
        for (int g = 0; g < 4; ++g) {
          f32x4v w;
          w[0] = o[dt][g * 4 + 0]; w[1] = o[dt][g * 4 + 1];
          w[2] = o[dt][g * 4 + 2]; w[3] = o[dt][g * 4 + 3];
          __builtin_nontemporal_store(w, (f32x4v*)(po + dt * 32 + g * 8 + hi4));
        }
      if (hi == 0) {
        __builtin_nontemporal_store(mrow, wsML + (size_t)slot * 256 + qloc);
        __builtin_nontemporal_store(lsum, wsML + (size_t)slot * 256 + 128 + qloc);
      }
    }
  }
}

__global__ __launch_bounds__(256)
void fa_merge_kernel(const float* __restrict__ wsO, const float* __restrict__ wsML,
                     float* __restrict__ out) {
  const int bid = blockIdx.x;          // bh*8 + c ; heavy tile qt = 15-c
  const int c = bid & 7, bh = bid >> 3;
  const int qt = 15 - c;
  const int t = threadIdx.x;
  const size_t s0 = (size_t)bid * 2;
  const float* O0 = wsO + (s0 + 0) * 16384;
  const float* O1 = wsO + (s0 + 1) * 16384;
  const float* M0 = wsML + (s0 + 0) * 256;
  const float* M1 = wsML + (s0 + 1) * 256;
  float* ob = out + ((size_t)bh * Ss + qt * 128) * Dd;
  #pragma unroll
  for (int i = 0; i < 16; ++i) {
    int e4 = t + 256 * i;              // float4 index in 128x128 tile
    int row = e4 >> 5, dof = (e4 & 31) * 4;
    float m0 = M0[row], l0 = M0[128 + row];
    float m1 = M1[row], l1 = M1[128 + row];
    float M = fmaxf(m0, m1);
    float w0 = exp2hw(m0 - M), w1 = exp2hw(m1 - M);
    float Li = 1.0f / (l0 * w0 + l1 * w1);
    f32x4v a = __builtin_nontemporal_load((const f32x4v*)(O0 + (size_t)row * 128 + dof));
    f32x4v b = __builtin_nontemporal_load((const f32x4v*)(O1 + (size_t)row * 128 + dof));
    f32x4v r;
    r[0] = (a[0] * w0 + b[0] * w1) * Li; r[1] = (a[1] * w0 + b[1] * w1) * Li;
    r[2] = (a[2] * w0 + b[2] * w1) * Li; r[3] = (a[3] * w0 + b[3] * w1) * Li;
    *(f32x4v*)(ob + (size_t)row * Dd + dof) = r;
  }
}

extern "C" void kernel_launch(void* const* d_in, const int* in_sizes, int n_in,
                              void* d_out, int out_size, void* d_ws, size_t ws_size,
                              hipStream_t stream) {
  const float* q = (const float*)d_in[0];
  const float* k = (const float*)d_in[1];
  const float* v = (const float*)d_in[2];
  float* out = (float*)d_out;
  constexpr size_t SLOTS = 32 * 8 * 2;                      // 512
  constexpr size_t NEED_O  = SLOTS * 16384 * sizeof(float); // 32 MB
  constexpr size_t NEED_ML = SLOTS * 256 * sizeof(float);   // 0.5 MB
  const bool split = (d_ws != nullptr) && (ws_size >= NEED_O + NEED_ML);
  float* wsO  = split ? (float*)d_ws : nullptr;
  float* wsML = split ? ((float*)d_ws + SLOTS * 16384) : nullptr;
  dim3 block(256);
  hipLaunchKernelGGL(fa_seg_kernel, dim3(512), block, 0, stream, q, k, v, out, wsO, wsML);
  if (split)
    hipLaunchKernelGGL(fa_merge_kernel, dim3(256), block, 0, stream, wsO, wsML, out);
}